// Round 6
// baseline (138.735 us; speedup 1.0000x reference)
//
#include <hip/hip_runtime.h>
#include <hip/hip_bf16.h>

#define BB 4
#define CC 128
#define NN 4096
#define NHEAD 4
#define HDIM 32
#define KSPLIT 2   // attention m-dim split (DO NOT raise: KSPLIT=4 destroyed
                   // L2 reuse, FETCH 20->435MB, r2 post-mortem)

typedef short bf16x8_t __attribute__((ext_vector_type(8)));  // 8 bf16 (4 VGPRs)
typedef float f32x4_t __attribute__((ext_vector_type(4)));
typedef int i32x4_t __attribute__((ext_vector_type(4)));

#define MFMA16(a, b, c) __builtin_amdgcn_mfma_f32_16x16x32_bf16(a, b, c, 0, 0, 0)
#define EXP2(x) __builtin_amdgcn_exp2f(x)

// scores use exp2: fold log2(e) into q scale (softmax invariant)
#define QSCALE (0.17677669529663687f * 1.4426950408889634f)

// RNE float->bf16 (finite inputs only)
static __device__ inline unsigned short f2bf(float f) {
  unsigned u = __builtin_bit_cast(unsigned, f);
  u += 0x7fffu + ((u >> 16) & 1u);
  return (unsigned short)(u >> 16);
}
static __device__ inline unsigned pk2(float lo, float hi) {  // RNE pack pair
  return (unsigned)f2bf(lo) | ((unsigned)f2bf(hi) << 16);
}
// pack two f32 -> bf16 pair by TRUNCATION: single v_perm_b32
static __device__ inline unsigned pack_trunc(float lo, float hi) {
  return __builtin_amdgcn_perm(__builtin_bit_cast(unsigned, hi),
                               __builtin_bit_cast(unsigned, lo), 0x07060302u);
}

// async global->LDS, 16 B per lane. gsrc is PER-LANE (gather); LDS dest =
// uniform base + lane*16.
static __device__ inline void gload_lds16(const unsigned short* gsrc, void* ldst) {
  __builtin_amdgcn_global_load_lds(
      (const __attribute__((address_space(1))) unsigned int*)gsrc,
      (__attribute__((address_space(3))) unsigned int*)ldst, 16, 0, 0);
}

// ---------------------------------------------------------------------------
// W conversion: wq(*QSCALE), wk, wv, wo fp32 -> bf16, contiguous in wb.
// Tiny (~2us); pays for itself by letting qkv/out read W fragments straight
// from L2 with zero per-block staging (the r5 W-stage was ~150 VALU +
// 16 LDS writes per thread per block, on the pre-barrier critical path).
// ---------------------------------------------------------------------------
__global__ __launch_bounds__(256) void wconv_kernel(
    const float* __restrict__ wq, const float* __restrict__ wk,
    const float* __restrict__ wv, const float* __restrict__ wo,
    unsigned short* __restrict__ wb) {
  int f = (blockIdx.x * 256 + threadIdx.x) * 8;  // 32 blocks -> 65536 elems
  int m = f >> 14, off = f & 16383;
  const float* src = (m == 0) ? wq : (m == 1) ? wk : (m == 2) ? wv : wo;
  float sc = (m == 0) ? QSCALE : 1.0f;
  float4 a = *(const float4*)(src + off);
  float4 b = *(const float4*)(src + off + 4);
  ushort4 u0, u1;
  u0.x = f2bf(a.x * sc); u0.y = f2bf(a.y * sc); u0.z = f2bf(a.z * sc); u0.w = f2bf(a.w * sc);
  u1.x = f2bf(b.x * sc); u1.y = f2bf(b.y * sc); u1.z = f2bf(b.z * sc); u1.w = f2bf(b.w * sc);
  *(ushort4*)(wb + f) = u0;
  *(ushort4*)(wb + f + 4) = u1;
}

// ---------------------------------------------------------------------------
// QKV projection via MFMA. Grid (64 ntiles, B, 3 proj), 256 thr.
// x-tile staged fp32->bf16 into xsb [n][c] (the only LDS phase); W fragments
// read DIRECTLY from global bf16 wb inside the MFMA loop (L2-resident 32KB,
// broadcast across 768 blocks — r1-proven pattern). No W staging, no W
// barrier. vt (V transpose, proj==2) aliases xsb (dead after xf loads).
// Epilogues:
//   Q/K: pack 4 d into 2 dwords, shfl_xor(16) pair-exchange, even-g lanes
//        store one uint4 -> layout [b][h][dblk=d/8][n][8d] bf16.
//   V:   block LDS transpose [o][n] -> vg gathered tiles, sequential uint4.
// LDS ~17.4KB.
// ---------------------------------------------------------------------------
__global__ __launch_bounds__(256) void qkv_mfma_kernel(
    const float* __restrict__ x,
    const unsigned short* __restrict__ wqb, const unsigned short* __restrict__ wkb,
    const unsigned short* __restrict__ wvb,
    const float* __restrict__ bq, const float* __restrict__ bk,
    const float* __restrict__ bv,
    unsigned short* __restrict__ qt, unsigned short* __restrict__ kt,
    unsigned short* __restrict__ vg) {
  __shared__ __attribute__((aligned(16))) unsigned short xsb[64][136];   // 17.4KB
  unsigned short(*vt)[66] = (unsigned short(*)[66]) & xsb[0][0];  // alias (16.9KB)

  const int b = blockIdx.y, nt = blockIdx.x, proj = blockIdx.z;
  const int tid = threadIdx.x;

  // stage x-tile: [n][c] bf16 transpose
#pragma unroll
  for (int i = 0; i < 8; i++) {
    int f = tid + 256 * i;  // 2048 float4 slots
    int c = f >> 4, n4 = (f & 15) * 4;
    float4 v4 = *(const float4*)(x + ((size_t)b * CC + c) * NN + nt * 64 + n4);
    xsb[n4 + 0][c] = f2bf(v4.x);
    xsb[n4 + 1][c] = f2bf(v4.y);
    xsb[n4 + 2][c] = f2bf(v4.z);
    xsb[n4 + 3][c] = f2bf(v4.w);
  }
  __syncthreads();

  const int lane = tid & 63, w = tid >> 6;
  const int l16 = lane & 15, g = lane >> 4;
  const int nl = w * 16;
  const int ngl = nt * 64 + nl;

  bf16x8_t xf[4];
#pragma unroll
  for (int ks = 0; ks < 4; ks++)
    xf[ks] = *(const bf16x8_t*)&xsb[nl + l16][ks * 32 + g * 8];
  __syncthreads();  // xsb dead; vt (alias) may now be written

  const unsigned short* wm = (proj == 0) ? wqb : (proj == 1) ? wkb : wvb;
  const float* bias = (proj == 0) ? bq : (proj == 1) ? bk : bv;
  const float bsc = (proj == 0) ? QSCALE : 1.0f;
  unsigned short* qkdst = proj ? kt : qt;

#pragma unroll
  for (int ot = 0; ot < 8; ot++) {
    f32x4_t acc;
#pragma unroll
    for (int r = 0; r < 4; r++) acc[r] = bias[ot * 16 + g * 4 + r] * bsc;
#pragma unroll
    for (int ks = 0; ks < 4; ks++) {
      bf16x8_t wf = *(const bf16x8_t*)(wm + (size_t)(ot * 16 + l16) * CC + ks * 32 + g * 8);
      acc = MFMA16(wf, xf[ks], acc);
    }
    if (proj < 2) {
      // lane holds d = (ot&15 base) consecutive 4; pair with g^1 for 8
      unsigned p0 = pk2(acc[0], acc[1]);
      unsigned p1 = pk2(acc[2], acc[3]);
      unsigned q0 = (unsigned)__shfl_xor((int)p0, 16);
      unsigned q1 = (unsigned)__shfl_xor((int)p1, 16);
      if ((g & 1) == 0) {
        int hh = ot >> 1, dblk = (ot & 1) * 2 + (g >> 1);
        unsigned short* dst =
            qkdst + (((size_t)(b * NHEAD + hh) * 4 + dblk) * NN + ngl + l16) * 8;
        uint4 val = make_uint4(p0, p1, q0, q1);
        *(uint4*)dst = val;
      }
    } else {
#pragma unroll
      for (int r = 0; r < 4; r++) vt[ot * 16 + g * 4 + r][nl + l16] = f2bf(acc[r]);
    }
  }

  if (proj == 2) {
    __syncthreads();
    // emit vg: 1024 16B chunks, perfectly sequential stores
#pragma unroll
    for (int c = 0; c < 4; c++) {
      int cid = c * 256 + tid;
      int hh = cid >> 8, inner = cid & 255;
      int g2 = inner & 3, l16v = (inner >> 2) & 15, fh = inner >> 6;
      int fv = fh >> 1, half = fh & 1;
      int o = hh * 32 + half * 16 + l16v;
      int n0 = fv * 32 + g2 * 4;
      unsigned d0 = *(const unsigned*)&vt[o][n0];
      unsigned d1 = *(const unsigned*)&vt[o][n0 + 2];
      unsigned d2 = *(const unsigned*)&vt[o][n0 + 16];
      unsigned d3 = *(const unsigned*)&vt[o][n0 + 18];
      uint4 val = make_uint4(d0, d1, d2, d3);
      *(uint4*)(vg + (((size_t)(b * NHEAD + hh) * 64 + nt) * 256 + inner) * 8) = val;
    }
  }
}

// ---------------------------------------------------------------------------
// Flash attention, bf16 MFMA — unchanged from r5 (KSPLIT=2, setprio around
// MFMA clusters, bf16-packed opart with full-line store geometry).
// ---------------------------------------------------------------------------
__global__ __launch_bounds__(256, 4) void attn_mfma5_kernel(
    const unsigned short* __restrict__ qt, const unsigned short* __restrict__ kt,
    const unsigned short* __restrict__ vg,
    unsigned* __restrict__ opart, float* __restrict__ lpart) {
  __shared__ __attribute__((aligned(16))) unsigned short smem[2][4096];  // [buf]: K 2048, V 2048

  const int chunk = blockIdx.x & (KSPLIT - 1), nt = blockIdx.x / KSPLIT;
  const int h = blockIdx.y, b = blockIdx.z;
  const int bh = b * NHEAD + h;
  const int tid = threadIdx.x, lane = tid & 63, wid = tid >> 6;
  const int l16 = lane & 15, g = lane >> 4;
  const int nbase = nt * 128 + wid * 32;

  const unsigned short* qb = qt + (size_t)bh * NN * HDIM;  // [dblk][n][8]
  const unsigned short* kb = kt + (size_t)bh * NN * HDIM;
  const unsigned short* vgb = vg + (size_t)bh * 64 * 2048;

  const bf16x8_t qf0 = *(const bf16x8_t*)(qb + ((size_t)g * NN + nbase + l16) * 8);
  const bf16x8_t qf1 = *(const bf16x8_t*)(qb + ((size_t)g * NN + nbase + 16 + l16) * 8);

  f32x4_t o00 = {0, 0, 0, 0}, o01 = {0, 0, 0, 0};  // t0: d=g*4+r, d+16
  f32x4_t o10 = {0, 0, 0, 0}, o11 = {0, 0, 0, 0};  // t1
  f32x4_t la = {0, 0, 0, 0}, lb = {0, 0, 0, 0};    // l sums via ones-MFMA
  const f32x4_t zf = {0, 0, 0, 0};
  const i32x4_t onesi = {0x3F803F80, 0x3F803F80, 0x3F803F80, 0x3F803F80};
  const bf16x8_t ones = __builtin_bit_cast(bf16x8_t, onesi);

  const int NITER = 64 / KSPLIT;
  const int mt0 = chunk * NITER;

  const unsigned short* ksrc = kb + ((size_t)g * NN + mt0 * 64 + wid * 16 + l16) * 8;
  const unsigned short* vsrc = vgb + (size_t)mt0 * 2048 + (size_t)((wid * 16 + l16) * 4 + g) * 8;

  auto stage = [&](int p, int i) {
    gload_lds16(ksrc + (size_t)i * 512, &smem[p][wid * 512]);
    gload_lds16(vsrc + (size_t)i * 2048, &smem[p][2048 + wid * 512]);
  };

  auto body = [&](int p) {
    const unsigned short* sk = &smem[p][0];
    bf16x8_t k0 = *(const bf16x8_t*)(sk + 0 * 512 + lane * 8);
    bf16x8_t k1 = *(const bf16x8_t*)(sk + 1 * 512 + lane * 8);
    bf16x8_t k2 = *(const bf16x8_t*)(sk + 2 * 512 + lane * 8);
    bf16x8_t k3 = *(const bf16x8_t*)(sk + 3 * 512 + lane * 8);
    bf16x8_t vf0 = *(const bf16x8_t*)(sk + 2048 + 0 * 512 + lane * 8);  // f0,h0
    bf16x8_t vf2 = *(const bf16x8_t*)(sk + 2048 + 1 * 512 + lane * 8);  // f0,h1
    bf16x8_t vf1 = *(const bf16x8_t*)(sk + 2048 + 2 * 512 + lane * 8);  // f1,h0
    bf16x8_t vf3 = *(const bf16x8_t*)(sk + 2048 + 3 * 512 + lane * 8);  // f1,h1

    __builtin_amdgcn_s_setprio(1);
    f32x4_t sA0 = MFMA16(k0, qf0, zf), sA1 = MFMA16(k1, qf0, zf);
    f32x4_t sA2 = MFMA16(k2, qf0, zf), sA3 = MFMA16(k3, qf0, zf);
    f32x4_t sB0 = MFMA16(k0, qf1, zf), sB1 = MFMA16(k1, qf1, zf);
    f32x4_t sB2 = MFMA16(k2, qf1, zf), sB3 = MFMA16(k3, qf1, zf);
    __builtin_amdgcn_s_setprio(0);

#pragma unroll
    for (int r = 0; r < 4; r++) {
      sA0[r] = EXP2(sA0[r]); sA1[r] = EXP2(sA1[r]);
      sA2[r] = EXP2(sA2[r]); sA3[r] = EXP2(sA3[r]);
      sB0[r] = EXP2(sB0[r]); sB1[r] = EXP2(sB1[r]);
      sB2[r] = EXP2(sB2[r]); sB3[r] = EXP2(sB3[r]);
    }

    i32x4_t pA0i = {(int)pack_trunc(sA0[0], sA0[1]), (int)pack_trunc(sA0[2], sA0[3]),
                    (int)pack_trunc(sA1[0], sA1[1]), (int)pack_trunc(sA1[2], sA1[3])};
    i32x4_t pA1i = {(int)pack_trunc(sA2[0], sA2[1]), (int)pack_trunc(sA2[2], sA2[3]),
                    (int)pack_trunc(sA3[0], sA3[1]), (int)pack_trunc(sA3[2], sA3[3])};
    i32x4_t pB0i = {(int)pack_trunc(sB0[0], sB0[1]), (int)pack_trunc(sB0[2], sB0[3]),
                    (int)pack_trunc(sB1[0], sB1[1]), (int)pack_trunc(sB1[2], sB1[3])};
    i32x4_t pB1i = {(int)pack_trunc(sB2[0], sB2[1]), (int)pack_trunc(sB2[2], sB2[3]),
                    (int)pack_trunc(sB3[0], sB3[1]), (int)pack_trunc(sB3[2], sB3[3])};
    bf16x8_t pA0 = __builtin_bit_cast(bf16x8_t, pA0i);
    bf16x8_t pA1 = __builtin_bit_cast(bf16x8_t, pA1i);
    bf16x8_t pB0 = __builtin_bit_cast(bf16x8_t, pB0i);
    bf16x8_t pB1 = __builtin_bit_cast(bf16x8_t, pB1i);

    __builtin_amdgcn_s_setprio(1);
    o00 = MFMA16(vf0, pA0, o00); o00 = MFMA16(vf1, pA1, o00);
    o01 = MFMA16(vf2, pA0, o01); o01 = MFMA16(vf3, pA1, o01);
    o10 = MFMA16(vf0, pB0, o10); o10 = MFMA16(vf1, pB1, o10);
    o11 = MFMA16(vf2, pB0, o11); o11 = MFMA16(vf3, pB1, o11);

    la = MFMA16(ones, pA0, la); la = MFMA16(ones, pA1, la);
    lb = MFMA16(ones, pB0, lb); lb = MFMA16(ones, pB1, lb);
    __builtin_amdgcn_s_setprio(0);
  };

  stage(0, 0);
  __syncthreads();
  for (int mi = 0; mi < NITER; mi += 2) {
    stage(1, mi + 1);
    body(0);
    __syncthreads();
    if (mi + 2 < NITER) stage(0, mi + 2);
    body(1);
    __syncthreads();
  }

  // write unnormalized partials, bf16-packed: opart[chunk][bh][cd] rows of
  // NN/2 dwords; dword (wnd*16 + j) holds (n = wnd*32+j, n = wnd*32+16+j).
  // Each quarter (16 lanes) stores 64 contiguous aligned bytes.
  unsigned* ob32 = opart + ((size_t)(chunk * BB * NHEAD + bh)) * HDIM * (NN / 2);
  const int wnd16 = (nbase >> 5) * 16;  // dword base of this wave's window
#pragma unroll
  for (int r = 0; r < 4; r++) {
    ob32[(size_t)(g * 4 + r) * (NN / 2) + wnd16 + l16] = pk2(o00[r], o10[r]);
    ob32[(size_t)(16 + g * 4 + r) * (NN / 2) + wnd16 + l16] = pk2(o01[r], o11[r]);
  }
  if (g == 0) {
    float* lb_ = lpart + (size_t)(chunk * BB * NHEAD + bh) * NN;
    lb_[nbase + l16] = la[0];
    lb_[nbase + 16 + l16] = lb[0];
  }
}

// ---------------------------------------------------------------------------
// Output projection fused with partial-combine — reads bf16-packed opart +
// lpart, sums KSPLIT chunks, normalizes, packs bf16 into xsb [n][c]; wo
// fragments read DIRECTLY from global bf16 wob (L2-resident, no LDS stage).
// MFMA + bias + residual, fp32 out. Grid (64 ntiles, B), 512 thr:
// 8 waves = (4 n-subtiles) x (2 mt-halves). LDS ~18.4KB.
// ---------------------------------------------------------------------------
__global__ __launch_bounds__(512) void out_mfma_kernel(
    const unsigned* __restrict__ opart, const float* __restrict__ lpart,
    const unsigned short* __restrict__ wob, const float* __restrict__ bo,
    const float* __restrict__ x, float* __restrict__ out) {
  __shared__ __attribute__((aligned(16))) unsigned short xsb[64][136];   // 17.4KB
  __shared__ float linv[NHEAD][64];
  const int b = blockIdx.y, nt = blockIdx.x;
  const int tid = threadIdx.x;

  if (tid < 256) {  // 1/l per (h, n)
    int h = tid >> 6, nn = tid & 63;
    int bh = b * NHEAD + h;
    float l = 0.f;
#pragma unroll
    for (int c = 0; c < KSPLIT; c++)
      l += lpart[(size_t)(c * BB * NHEAD + bh) * NN + nt * 64 + nn];
    linv[h][nn] = 1.f / l;
  }
  __syncthreads();

  // combine + normalize + bf16-pack into LDS from packed opart.
  // Row cd has NN/2 dwords; tile covers dwords [nt*32, nt*32+32) = 8 uint4.
  // uint4 slot q (0..7): local window (q>>2), j = (q&3)*4; dword e holds
  // (n_lo = (q>>2)*32 + j + e, n_hi = n_lo + 16).
  const size_t ROWD = NN / 2;
  const size_t CH32 = (size_t)BB * NHEAD * HDIM * ROWD;  // chunk stride (dwords)
  const unsigned* obb = opart + (size_t)b * NHEAD * HDIM * ROWD;
#pragma unroll
  for (int i = 0; i < 2; i++) {
    int s = i * 512 + tid;  // 1024 uint4 slots (128 cd x 8)
    int cd = s >> 3, q = s & 7;
    size_t a = (size_t)cd * ROWD + nt * 32 + q * 4;
    uint4 u0 = *(const uint4*)(obb + a);
    uint4 u1 = *(const uint4*)(obb + CH32 + a);
    int nb = (q >> 2) * 32 + (q & 3) * 4;  // local n base (lo half)
    const float* li = &linv[cd >> 5][0];
    const unsigned* w0 = (const unsigned*)&u0;
    const unsigned* w1 = (const unsigned*)&u1;
#pragma unroll
    for (int e = 0; e < 4; e++) {
      float lo = __builtin_bit_cast(float, w0[e] << 16) +
                 __builtin_bit_cast(float, w1[e] << 16);
      float hi = __builtin_bit_cast(float, w0[e] & 0xFFFF0000u) +
                 __builtin_bit_cast(float, w1[e] & 0xFFFF0000u);
      int nl = nb + e;
      xsb[nl][cd] = f2bf(lo * li[nl]);
      xsb[nl + 16][cd] = f2bf(hi * li[nl + 16]);
    }
  }
  __syncthreads();

  const int lane = tid & 63, w = tid >> 6;
  const int l16 = lane & 15, g = lane >> 4;
  const int nsub = (w & 3) * 16, mtbase = (w >> 2) * 4;
  const int n0 = nt * 64 + nsub;

  bf16x8_t bfr[4];
#pragma unroll
  for (int ks = 0; ks < 4; ks++)
    bfr[ks] = *(const bf16x8_t*)&xsb[nsub + l16][ks * 32 + g * 8];

#pragma unroll
  for (int mi = 0; mi < 4; mi++) {
    int mt = mtbase + mi;
    f32x4_t acc;
#pragma unroll
    for (int r = 0; r < 4; r++) acc[r] = bo[mt * 16 + g * 4 + r];
#pragma unroll
    for (int ks = 0; ks < 4; ks++) {
      bf16x8_t af = *(const bf16x8_t*)(wob + (size_t)(mt * 16 + l16) * CC + ks * 32 + g * 8);
      acc = MFMA16(af, bfr[ks], acc);
    }
#pragma unroll
    for (int r = 0; r < 4; r++) {
      int o = mt * 16 + g * 4 + r;
      size_t addr = ((size_t)b * CC + o) * NN + n0 + l16;
      out[addr] = acc[r] + x[addr];
    }
  }
}

extern "C" void kernel_launch(void* const* d_in, const int* in_sizes, int n_in,
                              void* d_out, int out_size, void* d_ws, size_t ws_size,
                              hipStream_t stream) {
  const float* x  = (const float*)d_in[0];
  const float* wq = (const float*)d_in[1];
  const float* bq = (const float*)d_in[2];
  const float* wk = (const float*)d_in[3];
  const float* bk = (const float*)d_in[4];
  const float* wv = (const float*)d_in[5];
  const float* bv = (const float*)d_in[6];
  const float* wo = (const float*)d_in[7];
  const float* bo = (const float*)d_in[8];
  float* out = (float*)d_out;

  char* w = (char*)d_ws;
  const size_t SZ = (size_t)BB * NHEAD * NN * HDIM * 2;  // 4 MB (bf16 buffer bytes)
  unsigned short* qt    = (unsigned short*)w;            // 4 MB
  unsigned short* kt    = (unsigned short*)(w + SZ);     // 4 MB
  unsigned short* vg    = (unsigned short*)(w + 2 * SZ); // 4 MB (gathered V)
  unsigned short* wb    = (unsigned short*)(w + 3 * SZ); // 128 KB
  unsigned* opart = (unsigned*)(w + 3 * SZ + 131072);    // KSPLIT * 4 MB (bf16 packed)
  float* lpart = (float*)(w + 3 * SZ + 131072 +
                          (size_t)KSPLIT * BB * NHEAD * HDIM * NN * 2);  // KSPLIT * 256 KB
  unsigned short* wqb = wb, *wkb = wb + 16384, *wvb = wb + 32768, *wob = wb + 49152;

  wconv_kernel<<<32, 256, 0, stream>>>(wq, wk, wv, wo, wb);
  qkv_mfma_kernel<<<dim3(NN / 64, BB, 3), 256, 0, stream>>>(
      x, wqb, wkb, wvb, bq, bk, bv, qt, kt, vg);
  attn_mfma5_kernel<<<dim3((NN / 128) * KSPLIT, NHEAD, BB), 256, 0, stream>>>(
      qt, kt, vg, opart, lpart);
  out_mfma_kernel<<<dim3(NN / 64, BB), 512, 0, stream>>>(
      opart, lpart, wob, bo, x, out);
}

// Round 8
// 128.181 us; speedup vs baseline: 1.0823x; 1.0823x over previous
//
#include <hip/hip_runtime.h>
#include <hip/hip_bf16.h>

#define BB 4
#define CC 128
#define NN 4096
#define NHEAD 4
#define HDIM 32
#define KSPLIT 2   // attention m-dim split (DO NOT raise: KSPLIT=4 destroyed
                   // L2 reuse, FETCH 20->435MB, r2 post-mortem)
// r6 lesson: W fragments must stay in LDS (global W reads serialized the
// MFMA loop, +8.7us).
// r7 lesson: qkv@512thr (wave ot-split) FAILED replay verification with an
// unexplained race — reverted to the r5 256-thr structure. Do not re-try
// the 8-wave split without a proven-race-free derivation.

typedef short bf16x8_t __attribute__((ext_vector_type(8)));  // 8 bf16 (4 VGPRs)
typedef float f32x4_t __attribute__((ext_vector_type(4)));
typedef int i32x4_t __attribute__((ext_vector_type(4)));

#define MFMA16(a, b, c) __builtin_amdgcn_mfma_f32_16x16x32_bf16(a, b, c, 0, 0, 0)
#define EXP2(x) __builtin_amdgcn_exp2f(x)

// scores use exp2: fold log2(e) into q scale (softmax invariant)
#define QSCALE (0.17677669529663687f * 1.4426950408889634f)

// RNE float->bf16 (finite inputs only)
static __device__ inline unsigned short f2bf(float f) {
  unsigned u = __builtin_bit_cast(unsigned, f);
  u += 0x7fffu + ((u >> 16) & 1u);
  return (unsigned short)(u >> 16);
}
static __device__ inline unsigned pk2(float lo, float hi) {  // RNE pack pair
  return (unsigned)f2bf(lo) | ((unsigned)f2bf(hi) << 16);
}
// pack two f32 -> bf16 pair by TRUNCATION: single v_perm_b32
static __device__ inline unsigned pack_trunc(float lo, float hi) {
  return __builtin_amdgcn_perm(__builtin_bit_cast(unsigned, hi),
                               __builtin_bit_cast(unsigned, lo), 0x07060302u);
}

// async global->LDS, 16 B per lane. gsrc is PER-LANE (gather); LDS dest =
// uniform base + lane*16.
static __device__ inline void gload_lds16(const unsigned short* gsrc, void* ldst) {
  __builtin_amdgcn_global_load_lds(
      (const __attribute__((address_space(1))) unsigned int*)gsrc,
      (__attribute__((address_space(3))) unsigned int*)ldst, 16, 0, 0);
}

// ---------------------------------------------------------------------------
// QKV projection via MFMA — r5 structure (256 thr, 4 waves), grid (64, B, 3).
// x-tile HBM loads issued FIRST (latency ahead of the L2-resident W reads),
// then W fp32->bf16 into wsb (packed uint2 stores). vt (V transpose,
// proj==2 only) aliases xsb (dead after the xf loads; barrier-2 separates).
// Epilogues:
//   Q/K: pack 4 d into 2 dwords, shfl_xor(16) pair-exchange, even-g lanes
//        store one uint4 -> layout [b][h][dblk=d/8][n][8d] bf16.
//   V:   block LDS transpose [o][n] -> vg gathered tiles, sequential uint4.
// LDS ~52.2KB -> 3 blocks/CU (768 blocks all resident).
// ---------------------------------------------------------------------------
__global__ __launch_bounds__(256) void qkv_mfma_kernel(
    const float* __restrict__ x,
    const float* __restrict__ wq, const float* __restrict__ wk,
    const float* __restrict__ wv,
    const float* __restrict__ bq, const float* __restrict__ bk,
    const float* __restrict__ bv,
    unsigned short* __restrict__ qt, unsigned short* __restrict__ kt,
    unsigned short* __restrict__ vg) {
  __shared__ __attribute__((aligned(16))) unsigned short wsb[128][136];  // 34.8KB
  __shared__ __attribute__((aligned(16))) unsigned short xsb[64][136];   // 17.4KB
  unsigned short(*vt)[66] = (unsigned short(*)[66]) & xsb[0][0];  // alias (16.9KB)

  const int b = blockIdx.y, nt = blockIdx.x, proj = blockIdx.z;
  const int tid = threadIdx.x;

  const float* wsrc = (proj == 0) ? wq : (proj == 1) ? wk : wv;
  const float wscale = (proj == 0) ? QSCALE : 1.0f;

  // stage x-tile first (HBM): [n][c] bf16 transpose
#pragma unroll
  for (int i = 0; i < 8; i++) {
    int f = tid + 256 * i;  // 2048 float4 slots
    int c = f >> 4, n4 = (f & 15) * 4;
    float4 v4 = *(const float4*)(x + ((size_t)b * CC + c) * NN + nt * 64 + n4);
    xsb[n4 + 0][c] = f2bf(v4.x);
    xsb[n4 + 1][c] = f2bf(v4.y);
    xsb[n4 + 2][c] = f2bf(v4.z);
    xsb[n4 + 3][c] = f2bf(v4.w);
  }

  // stage W: 4096 float4 over 256 thr, coalesced reads, packed b64 LDS writes
#pragma unroll
  for (int i = 0; i < 16; i++) {
    int idx = i * 256 + tid;           // float4 index
    int o = idx >> 5, c4 = (idx & 31) * 4;
    float4 v4 = *(const float4*)(wsrc + (size_t)o * CC + c4);
    uint2 p;
    p.x = pk2(v4.x * wscale, v4.y * wscale);
    p.y = pk2(v4.z * wscale, v4.w * wscale);
    *(uint2*)&wsb[o][c4] = p;  // 8B aligned: 136*2 % 8 == 0, c4*2 % 8 == 0
  }
  __syncthreads();

  const int lane = tid & 63, w = tid >> 6;
  const int l16 = lane & 15, g = lane >> 4;
  const int nl = w * 16;
  const int ngl = nt * 64 + nl;

  bf16x8_t xf[4];
#pragma unroll
  for (int ks = 0; ks < 4; ks++)
    xf[ks] = *(const bf16x8_t*)&xsb[nl + l16][ks * 32 + g * 8];
  __syncthreads();  // xsb dead; vt (alias) may now be written

  const float* bias = (proj == 0) ? bq : (proj == 1) ? bk : bv;
  const float bsc = (proj == 0) ? QSCALE : 1.0f;
  unsigned short* qkdst = proj ? kt : qt;

#pragma unroll
  for (int ot = 0; ot < 8; ot++) {
    f32x4_t acc;
#pragma unroll
    for (int r = 0; r < 4; r++) acc[r] = bias[ot * 16 + g * 4 + r] * bsc;
#pragma unroll
    for (int ks = 0; ks < 4; ks++) {
      bf16x8_t wf = *(const bf16x8_t*)&wsb[ot * 16 + l16][ks * 32 + g * 8];
      acc = MFMA16(wf, xf[ks], acc);
    }
    if (proj < 2) {
      // lane holds d = (ot&15 base) consecutive 4; pair with g^1 for 8
      unsigned p0 = pk2(acc[0], acc[1]);
      unsigned p1 = pk2(acc[2], acc[3]);
      unsigned q0 = (unsigned)__shfl_xor((int)p0, 16);
      unsigned q1 = (unsigned)__shfl_xor((int)p1, 16);
      if ((g & 1) == 0) {
        int hh = ot >> 1, dblk = (ot & 1) * 2 + (g >> 1);
        unsigned short* dst =
            qkdst + (((size_t)(b * NHEAD + hh) * 4 + dblk) * NN + ngl + l16) * 8;
        uint4 val = make_uint4(p0, p1, q0, q1);
        *(uint4*)dst = val;
      }
    } else {
#pragma unroll
      for (int r = 0; r < 4; r++) vt[ot * 16 + g * 4 + r][nl + l16] = f2bf(acc[r]);
    }
  }

  if (proj == 2) {
    __syncthreads();
    // emit vg: 1024 16B chunks, perfectly sequential stores
#pragma unroll
    for (int c = 0; c < 4; c++) {
      int cid = c * 256 + tid;
      int hh = cid >> 8, inner = cid & 255;
      int g2 = inner & 3, l16v = (inner >> 2) & 15, fh = inner >> 6;
      int fv = fh >> 1, half = fh & 1;
      int o = hh * 32 + half * 16 + l16v;
      int n0 = fv * 32 + g2 * 4;
      unsigned d0 = *(const unsigned*)&vt[o][n0];
      unsigned d1 = *(const unsigned*)&vt[o][n0 + 2];
      unsigned d2 = *(const unsigned*)&vt[o][n0 + 16];
      unsigned d3 = *(const unsigned*)&vt[o][n0 + 18];
      uint4 val = make_uint4(d0, d1, d2, d3);
      *(uint4*)(vg + (((size_t)(b * NHEAD + hh) * 64 + nt) * 256 + inner) * 8) = val;
    }
  }
}

// ---------------------------------------------------------------------------
// Flash attention, bf16 MFMA — unchanged from r5 (KSPLIT=2, setprio around
// MFMA clusters, bf16-packed opart with full-line store geometry).
// ---------------------------------------------------------------------------
__global__ __launch_bounds__(256, 4) void attn_mfma5_kernel(
    const unsigned short* __restrict__ qt, const unsigned short* __restrict__ kt,
    const unsigned short* __restrict__ vg,
    unsigned* __restrict__ opart, float* __restrict__ lpart) {
  __shared__ __attribute__((aligned(16))) unsigned short smem[2][4096];  // [buf]: K 2048, V 2048

  const int chunk = blockIdx.x & (KSPLIT - 1), nt = blockIdx.x / KSPLIT;
  const int h = blockIdx.y, b = blockIdx.z;
  const int bh = b * NHEAD + h;
  const int tid = threadIdx.x, lane = tid & 63, wid = tid >> 6;
  const int l16 = lane & 15, g = lane >> 4;
  const int nbase = nt * 128 + wid * 32;

  const unsigned short* qb = qt + (size_t)bh * NN * HDIM;  // [dblk][n][8]
  const unsigned short* kb = kt + (size_t)bh * NN * HDIM;
  const unsigned short* vgb = vg + (size_t)bh * 64 * 2048;

  const bf16x8_t qf0 = *(const bf16x8_t*)(qb + ((size_t)g * NN + nbase + l16) * 8);
  const bf16x8_t qf1 = *(const bf16x8_t*)(qb + ((size_t)g * NN + nbase + 16 + l16) * 8);

  f32x4_t o00 = {0, 0, 0, 0}, o01 = {0, 0, 0, 0};  // t0: d=g*4+r, d+16
  f32x4_t o10 = {0, 0, 0, 0}, o11 = {0, 0, 0, 0};  // t1
  f32x4_t la = {0, 0, 0, 0}, lb = {0, 0, 0, 0};    // l sums via ones-MFMA
  const f32x4_t zf = {0, 0, 0, 0};
  const i32x4_t onesi = {0x3F803F80, 0x3F803F80, 0x3F803F80, 0x3F803F80};
  const bf16x8_t ones = __builtin_bit_cast(bf16x8_t, onesi);

  const int NITER = 64 / KSPLIT;
  const int mt0 = chunk * NITER;

  const unsigned short* ksrc = kb + ((size_t)g * NN + mt0 * 64 + wid * 16 + l16) * 8;
  const unsigned short* vsrc = vgb + (size_t)mt0 * 2048 + (size_t)((wid * 16 + l16) * 4 + g) * 8;

  auto stage = [&](int p, int i) {
    gload_lds16(ksrc + (size_t)i * 512, &smem[p][wid * 512]);
    gload_lds16(vsrc + (size_t)i * 2048, &smem[p][2048 + wid * 512]);
  };

  auto body = [&](int p) {
    const unsigned short* sk = &smem[p][0];
    bf16x8_t k0 = *(const bf16x8_t*)(sk + 0 * 512 + lane * 8);
    bf16x8_t k1 = *(const bf16x8_t*)(sk + 1 * 512 + lane * 8);
    bf16x8_t k2 = *(const bf16x8_t*)(sk + 2 * 512 + lane * 8);
    bf16x8_t k3 = *(const bf16x8_t*)(sk + 3 * 512 + lane * 8);
    bf16x8_t vf0 = *(const bf16x8_t*)(sk + 2048 + 0 * 512 + lane * 8);  // f0,h0
    bf16x8_t vf2 = *(const bf16x8_t*)(sk + 2048 + 1 * 512 + lane * 8);  // f0,h1
    bf16x8_t vf1 = *(const bf16x8_t*)(sk + 2048 + 2 * 512 + lane * 8);  // f1,h0
    bf16x8_t vf3 = *(const bf16x8_t*)(sk + 2048 + 3 * 512 + lane * 8);  // f1,h1

    __builtin_amdgcn_s_setprio(1);
    f32x4_t sA0 = MFMA16(k0, qf0, zf), sA1 = MFMA16(k1, qf0, zf);
    f32x4_t sA2 = MFMA16(k2, qf0, zf), sA3 = MFMA16(k3, qf0, zf);
    f32x4_t sB0 = MFMA16(k0, qf1, zf), sB1 = MFMA16(k1, qf1, zf);
    f32x4_t sB2 = MFMA16(k2, qf1, zf), sB3 = MFMA16(k3, qf1, zf);
    __builtin_amdgcn_s_setprio(0);

#pragma unroll
    for (int r = 0; r < 4; r++) {
      sA0[r] = EXP2(sA0[r]); sA1[r] = EXP2(sA1[r]);
      sA2[r] = EXP2(sA2[r]); sA3[r] = EXP2(sA3[r]);
      sB0[r] = EXP2(sB0[r]); sB1[r] = EXP2(sB1[r]);
      sB2[r] = EXP2(sB2[r]); sB3[r] = EXP2(sB3[r]);
    }

    i32x4_t pA0i = {(int)pack_trunc(sA0[0], sA0[1]), (int)pack_trunc(sA0[2], sA0[3]),
                    (int)pack_trunc(sA1[0], sA1[1]), (int)pack_trunc(sA1[2], sA1[3])};
    i32x4_t pA1i = {(int)pack_trunc(sA2[0], sA2[1]), (int)pack_trunc(sA2[2], sA2[3]),
                    (int)pack_trunc(sA3[0], sA3[1]), (int)pack_trunc(sA3[2], sA3[3])};
    i32x4_t pB0i = {(int)pack_trunc(sB0[0], sB0[1]), (int)pack_trunc(sB0[2], sB0[3]),
                    (int)pack_trunc(sB1[0], sB1[1]), (int)pack_trunc(sB1[2], sB1[3])};
    i32x4_t pB1i = {(int)pack_trunc(sB2[0], sB2[1]), (int)pack_trunc(sB2[2], sB2[3]),
                    (int)pack_trunc(sB3[0], sB3[1]), (int)pack_trunc(sB3[2], sB3[3])};
    bf16x8_t pA0 = __builtin_bit_cast(bf16x8_t, pA0i);
    bf16x8_t pA1 = __builtin_bit_cast(bf16x8_t, pA1i);
    bf16x8_t pB0 = __builtin_bit_cast(bf16x8_t, pB0i);
    bf16x8_t pB1 = __builtin_bit_cast(bf16x8_t, pB1i);

    __builtin_amdgcn_s_setprio(1);
    o00 = MFMA16(vf0, pA0, o00); o00 = MFMA16(vf1, pA1, o00);
    o01 = MFMA16(vf2, pA0, o01); o01 = MFMA16(vf3, pA1, o01);
    o10 = MFMA16(vf0, pB0, o10); o10 = MFMA16(vf1, pB1, o10);
    o11 = MFMA16(vf2, pB0, o11); o11 = MFMA16(vf3, pB1, o11);

    la = MFMA16(ones, pA0, la); la = MFMA16(ones, pA1, la);
    lb = MFMA16(ones, pB0, lb); lb = MFMA16(ones, pB1, lb);
    __builtin_amdgcn_s_setprio(0);
  };

  stage(0, 0);
  __syncthreads();
  for (int mi = 0; mi < NITER; mi += 2) {
    stage(1, mi + 1);
    body(0);
    __syncthreads();
    if (mi + 2 < NITER) stage(0, mi + 2);
    body(1);
    __syncthreads();
  }

  // write unnormalized partials, bf16-packed: opart[chunk][bh][cd] rows of
  // NN/2 dwords; dword (wnd*16 + j) holds (n = wnd*32+j, n = wnd*32+16+j).
  // Each quarter (16 lanes) stores 64 contiguous aligned bytes.
  unsigned* ob32 = opart + ((size_t)(chunk * BB * NHEAD + bh)) * HDIM * (NN / 2);
  const int wnd16 = (nbase >> 5) * 16;  // dword base of this wave's window
#pragma unroll
  for (int r = 0; r < 4; r++) {
    ob32[(size_t)(g * 4 + r) * (NN / 2) + wnd16 + l16] = pk2(o00[r], o10[r]);
    ob32[(size_t)(16 + g * 4 + r) * (NN / 2) + wnd16 + l16] = pk2(o01[r], o11[r]);
  }
  if (g == 0) {
    float* lb_ = lpart + (size_t)(chunk * BB * NHEAD + bh) * NN;
    lb_[nbase + l16] = la[0];
    lb_[nbase + 16 + l16] = lb[0];
  }
}

// ---------------------------------------------------------------------------
// Output projection fused with partial-combine — unchanged from r5. Reads
// bf16-packed opart + lpart, sums KSPLIT chunks, normalizes, packs bf16
// into xsb [n][c]; wo fp32->bf16 into wsb (packed b64 stores); MFMA + bias
// + residual, fp32 out. Grid (64 ntiles, B), 512 thr:
// 8 waves = (4 n-subtiles) x (2 mt-halves).
// ---------------------------------------------------------------------------
__global__ __launch_bounds__(512) void out_mfma_kernel(
    const unsigned* __restrict__ opart, const float* __restrict__ lpart,
    const float* __restrict__ wo, const float* __restrict__ bo,
    const float* __restrict__ x, float* __restrict__ out) {
  __shared__ __attribute__((aligned(16))) unsigned short wsb[128][136];  // 34.8KB
  __shared__ __attribute__((aligned(16))) unsigned short xsb[64][136];   // 17.4KB
  __shared__ float linv[NHEAD][64];
  const int b = blockIdx.y, nt = blockIdx.x;
  const int tid = threadIdx.x;

  // stage wo -> bf16 LDS: 4096 float4 over 512 thr, packed b64 LDS writes
#pragma unroll
  for (int i = 0; i < 8; i++) {
    int idx = i * 512 + tid;
    int o = idx >> 5, c4 = (idx & 31) * 4;
    float4 v4 = *(const float4*)(wo + (size_t)o * CC + c4);
    uint2 p;
    p.x = pk2(v4.x, v4.y);
    p.y = pk2(v4.z, v4.w);
    *(uint2*)&wsb[o][c4] = p;
  }

  if (tid < 256) {  // 1/l per (h, n)
    int h = tid >> 6, nn = tid & 63;
    int bh = b * NHEAD + h;
    float l = 0.f;
#pragma unroll
    for (int c = 0; c < KSPLIT; c++)
      l += lpart[(size_t)(c * BB * NHEAD + bh) * NN + nt * 64 + nn];
    linv[h][nn] = 1.f / l;
  }
  __syncthreads();

  // combine + normalize + bf16-pack into LDS from packed opart.
  // Row cd has NN/2 dwords; tile covers dwords [nt*32, nt*32+32) = 8 uint4.
  // uint4 slot q (0..7): local window (q>>2), j = (q&3)*4; dword e holds
  // (n_lo = (q>>2)*32 + j + e, n_hi = n_lo + 16).
  const size_t ROWD = NN / 2;
  const size_t CH32 = (size_t)BB * NHEAD * HDIM * ROWD;  // chunk stride (dwords)
  const unsigned* obb = opart + (size_t)b * NHEAD * HDIM * ROWD;
#pragma unroll
  for (int i = 0; i < 2; i++) {
    int s = i * 512 + tid;  // 1024 uint4 slots (128 cd x 8)
    int cd = s >> 3, q = s & 7;
    size_t a = (size_t)cd * ROWD + nt * 32 + q * 4;
    uint4 u0 = *(const uint4*)(obb + a);
    uint4 u1 = *(const uint4*)(obb + CH32 + a);
    int nb = (q >> 2) * 32 + (q & 3) * 4;  // local n base (lo half)
    const float* li = &linv[cd >> 5][0];
    const unsigned* w0 = (const unsigned*)&u0;
    const unsigned* w1 = (const unsigned*)&u1;
#pragma unroll
    for (int e = 0; e < 4; e++) {
      float lo = __builtin_bit_cast(float, w0[e] << 16) +
                 __builtin_bit_cast(float, w1[e] << 16);
      float hi = __builtin_bit_cast(float, w0[e] & 0xFFFF0000u) +
                 __builtin_bit_cast(float, w1[e] & 0xFFFF0000u);
      int nl = nb + e;
      xsb[nl][cd] = f2bf(lo * li[nl]);
      xsb[nl + 16][cd] = f2bf(hi * li[nl + 16]);
    }
  }
  __syncthreads();

  const int lane = tid & 63, w = tid >> 6;
  const int l16 = lane & 15, g = lane >> 4;
  const int nsub = (w & 3) * 16, mtbase = (w >> 2) * 4;
  const int n0 = nt * 64 + nsub;

  bf16x8_t bfr[4];
#pragma unroll
  for (int ks = 0; ks < 4; ks++)
    bfr[ks] = *(const bf16x8_t*)&xsb[nsub + l16][ks * 32 + g * 8];

#pragma unroll
  for (int mi = 0; mi < 4; mi++) {
    int mt = mtbase + mi;
    f32x4_t acc;
#pragma unroll
    for (int r = 0; r < 4; r++) acc[r] = bo[mt * 16 + g * 4 + r];
#pragma unroll
    for (int ks = 0; ks < 4; ks++) {
      bf16x8_t af = *(const bf16x8_t*)&wsb[mt * 16 + l16][ks * 32 + g * 8];
      acc = MFMA16(af, bfr[ks], acc);
    }
#pragma unroll
    for (int r = 0; r < 4; r++) {
      int o = mt * 16 + g * 4 + r;
      size_t addr = ((size_t)b * CC + o) * NN + n0 + l16;
      out[addr] = acc[r] + x[addr];
    }
  }
}

extern "C" void kernel_launch(void* const* d_in, const int* in_sizes, int n_in,
                              void* d_out, int out_size, void* d_ws, size_t ws_size,
                              hipStream_t stream) {
  const float* x  = (const float*)d_in[0];
  const float* wq = (const float*)d_in[1];
  const float* bq = (const float*)d_in[2];
  const float* wk = (const float*)d_in[3];
  const float* bk = (const float*)d_in[4];
  const float* wv = (const float*)d_in[5];
  const float* bv = (const float*)d_in[6];
  const float* wo = (const float*)d_in[7];
  const float* bo = (const float*)d_in[8];
  float* out = (float*)d_out;

  char* w = (char*)d_ws;
  const size_t SZ = (size_t)BB * NHEAD * NN * HDIM * 2;  // 4 MB (bf16 buffer bytes)
  unsigned short* qt    = (unsigned short*)w;            // 4 MB
  unsigned short* kt    = (unsigned short*)(w + SZ);     // 4 MB
  unsigned short* vg    = (unsigned short*)(w + 2 * SZ); // 4 MB (gathered V)
  unsigned* opart = (unsigned*)(w + 3 * SZ);             // KSPLIT * 4 MB (bf16 packed)
  float* lpart = (float*)(w + 3 * SZ +
                          (size_t)KSPLIT * BB * NHEAD * HDIM * NN * 2);  // KSPLIT * 256 KB

  qkv_mfma_kernel<<<dim3(NN / 64, BB, 3), 256, 0, stream>>>(
      x, wq, wk, wv, bq, bk, bv, qt, kt, vg);
  attn_mfma5_kernel<<<dim3((NN / 128) * KSPLIT, NHEAD, BB), 256, 0, stream>>>(
      qt, kt, vg, opart, lpart);
  out_mfma_kernel<<<dim3(NN / 64, BB), 512, 0, stream>>>(
      opart, lpart, wo, bo, x, out);
}